// Round 1
// baseline (249.087 us; speedup 1.0000x reference)
//
#include <hip/hip_runtime.h>
#include <hip/hip_bf16.h>

// Problem constants
#define B_SZ   32
#define IN_U   16
#define IC     2048
#define NJ     16      // num_units
#define NK     64      // unit_size
// W[i][j][k][u]: strides i:16384, j:1024, k:16, u:1  (floats)
// x[b][u][i]:    strides b:32768, u:2048, i:1

// Tiling
#define ICH    16          // i's per block
#define NCH    (IC/ICH)    // 128 i-chunks
#define JG     4           // j's per block
#define NJG    (NJ/JG)     // 4 j-groups
#define SOUT   (B_SZ*NJ*NK)  // 32768 output elements

// Main kernel: block (p = i-chunk, jg = j-group), 256 threads = (k:64, uq:4).
// Thread accumulates acc[b][jj] for all 32 b and 4 j's at fixed (k, u-quad).
__global__ __launch_bounds__(256, 2)
void caps_main(const float* __restrict__ x, const float* __restrict__ W,
               float* __restrict__ part) {
    const int tid = threadIdx.x;
    const int p   = blockIdx.x;   // i-chunk
    const int jg  = blockIdx.y;   // j-group
    const int i0  = p * ICH;

    // xs[ii][b][u] : u innermost so x[b, u0..u0+3, ii] is one ds_read_b128
    __shared__ float xs[ICH * B_SZ * IN_U];   // 8192 floats = 32 KB

    // Stage x chunk: 2048 float4 loads over 256 threads (8 each).
    // q -> row = q>>2 (b*16+u), ip = q&3 (which float4 of the 16-float row)
    #pragma unroll
    for (int it = 0; it < 8; ++it) {
        int q   = it * 256 + tid;
        int row = q >> 2;          // b*16 + u
        int ip  = q & 3;
        int b   = row >> 4;
        int u   = row & 15;
        float4 v = *(const float4*)(x + (size_t)row * IC + i0 + 4 * ip);
        int ii = 4 * ip;
        xs[(ii + 0) * 512 + b * 16 + u] = v.x;
        xs[(ii + 1) * 512 + b * 16 + u] = v.y;
        xs[(ii + 2) * 512 + b * 16 + u] = v.z;
        xs[(ii + 3) * 512 + b * 16 + u] = v.w;
    }
    __syncthreads();

    const int k  = tid >> 2;
    const int uq = tid & 3;

    float acc[B_SZ][JG];
    #pragma unroll
    for (int b = 0; b < B_SZ; ++b)
        #pragma unroll
        for (int j = 0; j < JG; ++j) acc[b][j] = 0.0f;

    // k*16 + uq*4 == 4*tid: thread t's W float4 sits at flat offset 4t
    const float* wbase = W + (size_t)i0 * 16384 + (size_t)(jg * JG) * 1024 + 4 * tid;

    #pragma unroll 2
    for (int ii = 0; ii < ICH; ++ii) {
        const float* wp = wbase + (size_t)ii * 16384;
        float4 w0 = *(const float4*)(wp);
        float4 w1 = *(const float4*)(wp + 1024);
        float4 w2 = *(const float4*)(wp + 2048);
        float4 w3 = *(const float4*)(wp + 3072);
        const float* xrow = xs + ii * 512 + uq * 4;
        #pragma unroll
        for (int b = 0; b < B_SZ; ++b) {
            float4 xv = *(const float4*)(xrow + (b << 4));
            acc[b][0] += w0.x * xv.x; acc[b][0] += w0.y * xv.y;
            acc[b][0] += w0.z * xv.z; acc[b][0] += w0.w * xv.w;
            acc[b][1] += w1.x * xv.x; acc[b][1] += w1.y * xv.y;
            acc[b][1] += w1.z * xv.z; acc[b][1] += w1.w * xv.w;
            acc[b][2] += w2.x * xv.x; acc[b][2] += w2.y * xv.y;
            acc[b][2] += w2.z * xv.z; acc[b][2] += w2.w * xv.w;
            acc[b][3] += w3.x * xv.x; acc[b][3] += w3.y * xv.y;
            acc[b][3] += w3.z * xv.z; acc[b][3] += w3.w * xv.w;
        }
    }

    // Combine the 4 u-quad lanes (lane bits 0-1) via butterfly shuffle.
    #pragma unroll
    for (int b = 0; b < B_SZ; ++b) {
        #pragma unroll
        for (int j = 0; j < JG; ++j) {
            float v = acc[b][j];
            v += __shfl_xor(v, 1, 64);
            v += __shfl_xor(v, 2, 64);
            acc[b][j] = v;
        }
    }

    if (uq == 0) {
        float* pp = part + (size_t)p * SOUT + k;
        #pragma unroll
        for (int b = 0; b < B_SZ; ++b)
            #pragma unroll
            for (int j = 0; j < JG; ++j)
                pp[(size_t)(b * NJ + jg * JG + j) * NK] = acc[b][j];
    }
}

// Sum the NCH partials: sbuf[gid] = sum_p part[p][gid]
__global__ __launch_bounds__(256)
void caps_reduce(const float* __restrict__ part, float* __restrict__ sbuf) {
    int gid = blockIdx.x * 256 + threadIdx.x;   // 128 blocks -> 32768 threads
    float s = 0.0f;
    #pragma unroll 8
    for (int p = 0; p < NCH; ++p) s += part[(size_t)p * SOUT + gid];
    sbuf[gid] = s;
}

// Squash: msq over j (num_units axis), out = s * mag/(1+msq)
__global__ __launch_bounds__(64)
void caps_squash(const float* __restrict__ sbuf, float* __restrict__ out) {
    int b = blockIdx.x;     // 32
    int k = threadIdx.x;    // 64
    float v[NJ];
    float msq = 0.0f;
    #pragma unroll
    for (int j = 0; j < NJ; ++j) {
        v[j] = sbuf[(size_t)(b * NJ + j) * NK + k];
        msq += v[j] * v[j];
    }
    float mag = sqrtf(msq);
    float f = mag / (1.0f + msq);
    #pragma unroll
    for (int j = 0; j < NJ; ++j)
        out[(size_t)(b * NJ + j) * NK + k] = v[j] * f;
}

extern "C" void kernel_launch(void* const* d_in, const int* in_sizes, int n_in,
                              void* d_out, int out_size, void* d_ws, size_t ws_size,
                              hipStream_t stream) {
    const float* x = (const float*)d_in[0];   // (32, 16, 2048) f32
    const float* W = (const float*)d_in[1];   // (1, 2048, 16, 64, 16) f32
    float* out  = (float*)d_out;              // (32, 16, 64) f32
    float* part = (float*)d_ws;                       // NCH * 32768 floats = 16 MB
    float* sbuf = part + (size_t)NCH * SOUT;          // + 128 KB

    caps_main  <<<dim3(NCH, NJG), 256, 0, stream>>>(x, W, part);
    caps_reduce<<<SOUT / 256,     256, 0, stream>>>(part, sbuf);
    caps_squash<<<B_SZ,           NK,  0, stream>>>(sbuf, out);
}

// Round 2
// 213.462 us; speedup vs baseline: 1.1669x; 1.1669x over previous
//
#include <hip/hip_runtime.h>
#include <hip/hip_bf16.h>

// Problem constants
#define B_SZ   32
#define IN_U   16
#define IC     2048
#define NJ     16      // num_units
#define NK     64      // unit_size
// W[i][j][k][u]: strides i:16384, j:1024, k:16, u:1  (floats)
// x[b][u][i]:    strides b:32768, u:2048, i:1

// Tiling
#define ICH    16          // i's per block
#define NCH    (IC/ICH)    // 128 i-chunks
#define JG     4           // j's per block
#define NJG    (NJ/JG)     // 4 j-groups
#define SOUT   (B_SZ*NJ*NK)  // 32768 output elements

// Main kernel: block (p = i-chunk, jg = j-group), 256 threads = 4 waves.
// Lane k (0..63) = unit_size index; wave bg (0..3) owns batches bg*8..bg*8+7.
// Each thread owns acc[8 batches][4 j] = 32 VGPRs (distinct outputs, no
// redundant accumulator copies -> no spill). x comes from LDS via
// wave-uniform broadcast reads (b,u uniform within a wave).
__global__ __launch_bounds__(256, 3)
void caps_main(const float* __restrict__ x, const float* __restrict__ W,
               float* __restrict__ part) {
    const int tid = threadIdx.x;
    const int p   = blockIdx.x;   // i-chunk
    const int jg  = blockIdx.y;   // j-group
    const int i0  = p * ICH;

    // xs[ii][b][u] : u innermost, row length 512 floats (b*16+u)
    __shared__ float xs[ICH * B_SZ * IN_U];   // 8192 floats = 32 KB

    // Stage x chunk: 2048 float4 loads over 256 threads (8 each).
    #pragma unroll
    for (int it = 0; it < 8; ++it) {
        int q   = it * 256 + tid;
        int row = q >> 2;          // b*16 + u
        int ip  = q & 3;
        float4 v = *(const float4*)(x + (size_t)row * IC + i0 + 4 * ip);
        int ii = 4 * ip;
        xs[(ii + 0) * 512 + row] = v.x;
        xs[(ii + 1) * 512 + row] = v.y;
        xs[(ii + 2) * 512 + row] = v.z;
        xs[(ii + 3) * 512 + row] = v.w;
    }
    __syncthreads();

    const int k  = tid & 63;     // lane
    const int bg = tid >> 6;     // wave id -> batch group

    float acc[8][JG];
    #pragma unroll
    for (int b = 0; b < 8; ++b)
        #pragma unroll
        for (int j = 0; j < JG; ++j) acc[b][j] = 0.0f;

    // W[i0+ii, jg*4+j, k, u]: per-lane base includes k*16
    const float* wbase = W + (size_t)i0 * 16384 + (size_t)(jg * JG) * 1024 + k * 16;

    #pragma unroll 1
    for (int ii = 0; ii < ICH; ++ii) {
        const float* wp = wbase + (size_t)ii * 16384;
        float4 w[JG][4];
        #pragma unroll
        for (int j = 0; j < JG; ++j)
            #pragma unroll
            for (int q = 0; q < 4; ++q)
                w[j][q] = *(const float4*)(wp + j * 1024 + q * 4);

        const float* xrow = xs + ii * 512 + bg * 128;   // batch base bg*8, *16 floats
        #pragma unroll
        for (int b = 0; b < 8; ++b) {
            #pragma unroll
            for (int q = 0; q < 4; ++q) {
                float4 xv = *(const float4*)(xrow + b * 16 + q * 4);  // broadcast
                #pragma unroll
                for (int j = 0; j < JG; ++j) {
                    acc[b][j] += w[j][q].x * xv.x;
                    acc[b][j] += w[j][q].y * xv.y;
                    acc[b][j] += w[j][q].z * xv.z;
                    acc[b][j] += w[j][q].w * xv.w;
                }
            }
        }
    }

    // Every thread owns distinct outputs: direct store, no shuffle/mask.
    float* pp = part + (size_t)p * SOUT + k;
    #pragma unroll
    for (int b = 0; b < 8; ++b)
        #pragma unroll
        for (int j = 0; j < JG; ++j)
            pp[(size_t)((bg * 8 + b) * NJ + jg * JG + j) * NK] = acc[b][j];
}

// Fused reduce + squash: one block per batch b (1024 threads = j*64 + k).
// s[b,j,k] = sum_p part[p][b,j,k]; msq over j; out = s * mag/(1+msq).
__global__ __launch_bounds__(1024)
void caps_finish(const float* __restrict__ part, float* __restrict__ out) {
    __shared__ float ls[NJ * NK];   // 1024 floats
    const int b = blockIdx.x;       // 32
    const int t = threadIdx.x;      // j*64 + k
    const int k = t & 63;

    const size_t base = (size_t)b * (NJ * NK) + t;
    float s = 0.0f;
    #pragma unroll 8
    for (int p = 0; p < NCH; ++p) s += part[(size_t)p * SOUT + base];
    ls[t] = s;
    __syncthreads();

    float msq = 0.0f;
    #pragma unroll
    for (int j = 0; j < NJ; ++j) {
        float v = ls[j * NK + k];
        msq += v * v;
    }
    float mag = sqrtf(msq);
    float f = mag / (1.0f + msq);
    out[base] = s * f;
}

extern "C" void kernel_launch(void* const* d_in, const int* in_sizes, int n_in,
                              void* d_out, int out_size, void* d_ws, size_t ws_size,
                              hipStream_t stream) {
    const float* x = (const float*)d_in[0];   // (32, 16, 2048) f32
    const float* W = (const float*)d_in[1];   // (1, 2048, 16, 64, 16) f32
    float* out  = (float*)d_out;              // (32, 16, 64) f32
    float* part = (float*)d_ws;               // NCH * 32768 floats = 16 MB

    caps_main  <<<dim3(NCH, NJG), 256,  0, stream>>>(x, W, part);
    caps_finish<<<B_SZ,           1024, 0, stream>>>(part, out);
}

// Round 3
// 201.873 us; speedup vs baseline: 1.2339x; 1.0574x over previous
//
#include <hip/hip_runtime.h>
#include <hip/hip_bf16.h>

// Problem: out[b,j,k] = squash_j( s[b,j,k] ), s = sum_{i<2048,u<16} W[i,j,k,u] x[b,u,i]
// GEMM view: C[m=b(32), n=(j,k)(1024)] = A[m,(i,u)] B[(i,u),n], K=32768.
// W[i][j][k][u] strides (floats): i:16384, j:1024, k:16, u:1
// x[b][u][i]    strides (floats): b:32768, u:2048, i:1

#define B_SZ   32
#define IC     2048
#define NJ     16
#define NK     64
#define SOUT   (B_SZ*NJ*NK)      // 32768
#define KSTEPS 1024              // K-steps; each covers kdim=32 = (2 i's x 16 u)
#define KSPLIT 32                // K-splits across grid.y
#define SPW    (KSTEPS/KSPLIT)   // 32 steps per wave

typedef float v4f __attribute__((ext_vector_type(4)));
typedef short v8s __attribute__((ext_vector_type(8)));

// f32 -> bf16 round-to-nearest-even (bit trick)
static __device__ inline ushort f2bf(float f) {
    uint32_t u = __float_as_uint(f);
    u += 0x7FFFu + ((u >> 16) & 1u);
    return (ushort)(u >> 16);
}

// ---------------------------------------------------------------------------
// xprep: build A-fragments in bf16.
// kdim enumeration within a step: kk = q*8 + jj  ->  i_off = kk>>4, u = kk&15.
// A-operand layout (16x16x32 bf16): lane holds A[m = lane&15][kk = (lane>>4)*8 + jj].
// xb flat: [step(1024)][mt(2)][lane(64)][jj(8)] bf16; value =
//   bf16( x[b = mt*16 + (lane&15)][u = (q&1)*8 + jj][i = 2*step + (q>>1)] )
// ---------------------------------------------------------------------------
__global__ __launch_bounds__(256)
void caps_xprep(const float* __restrict__ x, ushort* __restrict__ xb) {
    int gid  = blockIdx.x * 256 + threadIdx.x;   // 131072 threads
    int lane = gid & 63;
    int mt   = (gid >> 6) & 1;
    int step = gid >> 7;
    int q    = lane >> 4;
    int b    = mt * 16 + (lane & 15);
    int i    = 2 * step + (q >> 1);
    int u0   = (q & 1) * 8;

    const float* xp = x + (size_t)b * (16 * IC) + (size_t)u0 * IC + i;
    ushort tmp[8];
    #pragma unroll
    for (int jj = 0; jj < 8; ++jj)
        tmp[jj] = f2bf(xp[(size_t)jj * IC]);
    *(v8s*)(xb + (size_t)gid * 8) = *(const v8s*)tmp;   // coalesced 16 B/lane store
}

// ---------------------------------------------------------------------------
// main: block = (j, split), 256 thr = 4 waves; wave wv = k'-tile (16 k's).
// Per K-step: load 2 KB W f32 (coalesced, read-once), cvt->bf16 B-frag,
// 2 MFMA (two b-tiles). No LDS, no barriers.
// B-operand layout: lane holds B[kk = (lane>>4)*8 + jj][n = lane&15].
//   W addr: i = 2*step + (q>>1), u = (q&1)*8 + jj (8 consecutive floats).
// ---------------------------------------------------------------------------
__global__ __launch_bounds__(256)
void caps_mfma(const ushort* __restrict__ xb, const float* __restrict__ W,
               float* __restrict__ part) {
    const int tid   = threadIdx.x;
    const int wv    = tid >> 6;       // k'-tile 0..3
    const int lane  = tid & 63;
    const int j     = blockIdx.x;     // 0..15
    const int split = blockIdx.y;     // 0..KSPLIT-1
    const int n     = lane & 15;
    const int q     = lane >> 4;
    const int step0 = split * SPW;

    v4f acc0 = {0.f, 0.f, 0.f, 0.f};
    v4f acc1 = {0.f, 0.f, 0.f, 0.f};

    const float*  wp = W + (size_t)(2 * step0 + (q >> 1)) * 16384
                         + (size_t)j * 1024 + (size_t)(wv * 16 + n) * 16 + (q & 1) * 8;
    const ushort* xp = xb + (size_t)step0 * 1024 + (size_t)lane * 8;

    #pragma unroll 4
    for (int s = 0; s < SPW; ++s) {
        float4 w0 = *(const float4*)(wp);
        float4 w1 = *(const float4*)(wp + 4);
        v8s a0 = *(const v8s*)(xp);          // b-tile 0 (b 0..15)
        v8s a1 = *(const v8s*)(xp + 512);    // b-tile 1 (b 16..31)
        v8s bb;
        bb[0] = (short)f2bf(w0.x); bb[1] = (short)f2bf(w0.y);
        bb[2] = (short)f2bf(w0.z); bb[3] = (short)f2bf(w0.w);
        bb[4] = (short)f2bf(w1.x); bb[5] = (short)f2bf(w1.y);
        bb[6] = (short)f2bf(w1.z); bb[7] = (short)f2bf(w1.w);
        acc0 = __builtin_amdgcn_mfma_f32_16x16x32_bf16(a0, bb, acc0, 0, 0, 0);
        acc1 = __builtin_amdgcn_mfma_f32_16x16x32_bf16(a1, bb, acc1, 0, 0, 0);
        wp += 2 * 16384;
        xp += 1024;
    }

    // C/D layout: col = lane&15 = n (k'), row = q*4 + reg = m (b).
    // part[split][b][j][k] : k = wv*16 + n
    float* pp = part + (size_t)split * SOUT + (size_t)j * NK + wv * 16 + n;
    #pragma unroll
    for (int r = 0; r < 4; ++r) {
        int m = q * 4 + r;
        pp[(size_t)m * 1024]        = acc0[r];
        pp[(size_t)(m + 16) * 1024] = acc1[r];
    }
}

// ---------------------------------------------------------------------------
// finish: sum K-splits, then squash over j (num_units axis, per torch source).
// 128 blocks = (b:32, k-chunk:4); 256 thr = (j:16, kc:16).
// ---------------------------------------------------------------------------
__global__ __launch_bounds__(256)
void caps_finish(const float* __restrict__ part, float* __restrict__ out) {
    __shared__ float ls[256];
    const int blk = blockIdx.x;
    const int b   = blk >> 2;
    const int k0  = (blk & 3) * 16;
    const int t   = threadIdx.x;
    const int jj  = t >> 4;
    const int kc  = t & 15;
    const size_t idx = (size_t)b * 1024 + (size_t)jj * NK + k0 + kc;

    float s = 0.0f;
    #pragma unroll 8
    for (int sp = 0; sp < KSPLIT; ++sp)
        s += part[(size_t)sp * SOUT + idx];
    ls[t] = s;
    __syncthreads();

    float msq = 0.0f;
    #pragma unroll
    for (int j2 = 0; j2 < NJ; ++j2) {
        float v = ls[j2 * 16 + kc];
        msq += v * v;
    }
    float mag = sqrtf(msq);
    out[idx] = s * (mag / (1.0f + msq));
}

extern "C" void kernel_launch(void* const* d_in, const int* in_sizes, int n_in,
                              void* d_out, int out_size, void* d_ws, size_t ws_size,
                              hipStream_t stream) {
    const float* x = (const float*)d_in[0];   // (32, 16, 2048) f32
    const float* W = (const float*)d_in[1];   // (1, 2048, 16, 64, 16) f32
    float* out  = (float*)d_out;              // (32, 16, 64) f32

    float*  part = (float*)d_ws;                          // 4 MB
    ushort* xb   = (ushort*)(part + (size_t)KSPLIT * SOUT); // 2 MB

    caps_xprep <<<512,               256, 0, stream>>>(x, xb);
    caps_mfma  <<<dim3(16, KSPLIT),  256, 0, stream>>>(xb, W, part);
    caps_finish<<<128,               256, 0, stream>>>(part, out);
}